// Round 11
// baseline (14.191 us; speedup 1.0000x reference)
//
#include <hip/hip_runtime.h>

// MorphTEmbedding R11: R10 (nt stores, zero-DS) with the VMEM instruction
// count halved. Layout e = lane*8+j  =>  a=lane>>3, b=lane&7, c=j:
//  - A,B per-lane scalars: 16 broadcast dword loads (as before)
//  - C rows (wave-uniform 8x8 block): ONE gather load + v_readlane with
//    compile-time lane index r*8+j (R6's trick, applied to C)
//  - LN params: 4 dwordx4 loads; stores: 2 nontemporal dwordx4
// ~23 VMEM instrs/wave vs R10's ~41. LN reduce: DPP butterfly, zero DS.
// var = E[v^2]-mu^2 (var ~1e-12 << eps=1e-5; validated R2-R10).

#define RANK      8
#define NUM_MORPH 10000
#define EMB       512
#define LN_EPS    1e-5f
#define WPB       4                 // waves per block (256 threads)
#define RSTRIDE   80000             // floats between ranks in W

typedef float f32x4 __attribute__((ext_vector_type(4)));

template <int CTRL>
__device__ __forceinline__ float dpp_add(float v) {
    return v + __int_as_float(__builtin_amdgcn_update_dpp(
        __float_as_int(v), __float_as_int(v), CTRL, 0xf, 0xf, false));
}
__device__ __forceinline__ float rdlane(float v, int l) {
    return __int_as_float(__builtin_amdgcn_readlane(__float_as_int(v), l));
}

__global__ __launch_bounds__(256) void morph_emb_kernel(
    const int* __restrict__ x,       // [n_tok]
    const int* __restrict__ co,      // [NUM_SURF, 3]
    const float* __restrict__ W,     // [RANK, NUM_MORPH, 8]
    const float* __restrict__ lns,   // [512]
    const float* __restrict__ lnb,   // [512]
    float* __restrict__ out,         // [n_tok, 512]
    int n_tok) {
    const int lane = threadIdx.x & 63;
    const int wid  = blockIdx.x * WPB + (threadIdx.x >> 6);
    const int tok  = (wid < n_tok) ? wid : (n_tok - 1);   // clamp, no divergence

    // token chain (wave-uniform -> compiler emits s_load, zero VMEM)
    const int s  = x[tok];
    const int m0 = co[s * 3 + 0];
    const int m1 = co[s * 3 + 1];
    const int m2 = co[s * 3 + 2];

    // C distribution: lane (r=lane>>3, d=lane&7) holds W[r, m2, d] — ONE load
    const float c_mine =
        W[(size_t)(lane >> 3) * RSTRIDE + (size_t)m2 * 8 + (lane & 7)];

    // A,B per-lane scalars (broadcast loads, 32B footprint each)
    const float* pa = W + (size_t)m0 * 8 + (lane >> 3);
    const float* pb = W + (size_t)m1 * 8 + (lane & 7);
    float p[RANK];
#pragma unroll
    for (int r = 0; r < RANK; ++r)
        p[r] = pa[r * RSTRIDE] * pb[r * RSTRIDE];

    // LN params: e = lane*8 -> 4 dwordx4 loads
    const int e = lane << 3;
    const f32x4 g0 = *reinterpret_cast<const f32x4*>(lns + e);
    const f32x4 g1 = *reinterpret_cast<const f32x4*>(lns + e + 4);
    const f32x4 b0 = *reinterpret_cast<const f32x4*>(lnb + e);
    const f32x4 b1 = *reinterpret_cast<const f32x4*>(lnb + e + 4);

    // acc[j] = sum_r p[r] * C[r][j]; C via readlane (const idx) -> SGPR FMA
    float acc[8] = {0.f, 0.f, 0.f, 0.f, 0.f, 0.f, 0.f, 0.f};
#pragma unroll
    for (int r = 0; r < RANK; ++r) {
#pragma unroll
        for (int j = 0; j < 8; ++j)
            acc[j] = fmaf(p[r], rdlane(c_mine, r * 8 + j), acc[j]);
    }

    // ---- LayerNorm stats: DPP row-16 reduce + 4 readlanes (zero DS) ----
    float sm = 0.f, sq = 0.f;
#pragma unroll
    for (int j = 0; j < 8; ++j) { sm += acc[j]; sq += acc[j] * acc[j]; }
    sm = dpp_add<0xB1>(sm);  sq = dpp_add<0xB1>(sq);
    sm = dpp_add<0x4E>(sm);  sq = dpp_add<0x4E>(sq);
    sm = dpp_add<0x141>(sm); sq = dpp_add<0x141>(sq);
    sm = dpp_add<0x140>(sm); sq = dpp_add<0x140>(sq);
    const float tot_s = (rdlane(sm, 0) + rdlane(sm, 16)) +
                        (rdlane(sm, 32) + rdlane(sm, 48));
    const float tot_q = (rdlane(sq, 0) + rdlane(sq, 16)) +
                        (rdlane(sq, 32) + rdlane(sq, 48));
    const float mu = tot_s * (1.0f / EMB);
    const float rs = rsqrtf(tot_q * (1.0f / EMB) - mu * mu + LN_EPS);

    // ---- normalize + store: 2 nontemporal dwordx4 per lane ----
    if (wid < n_tok) {
        f32x4 o0, o1;
        o0[0] = (acc[0] - mu) * rs * g0[0] + b0[0];
        o0[1] = (acc[1] - mu) * rs * g0[1] + b0[1];
        o0[2] = (acc[2] - mu) * rs * g0[2] + b0[2];
        o0[3] = (acc[3] - mu) * rs * g0[3] + b0[3];
        o1[0] = (acc[4] - mu) * rs * g1[0] + b1[0];
        o1[1] = (acc[5] - mu) * rs * g1[1] + b1[1];
        o1[2] = (acc[6] - mu) * rs * g1[2] + b1[2];
        o1[3] = (acc[7] - mu) * rs * g1[3] + b1[3];
        f32x4* op = reinterpret_cast<f32x4*>(out + (size_t)wid * EMB + e);
        __builtin_nontemporal_store(o0, op);
        __builtin_nontemporal_store(o1, op + 1);
    }
}

extern "C" void kernel_launch(void* const* d_in, const int* in_sizes, int n_in,
                              void* d_out, int out_size, void* d_ws, size_t ws_size,
                              hipStream_t stream) {
    const int*   x   = (const int*)d_in[0];
    const int*   co  = (const int*)d_in[1];
    const float* W   = (const float*)d_in[2];
    const float* lns = (const float*)d_in[3];
    const float* lnb = (const float*)d_in[4];
    float*       out = (float*)d_out;

    const int n_tok  = in_sizes[0];                 // 16384
    const int blocks = (n_tok + WPB - 1) / WPB;     // 4096
    morph_emb_kernel<<<blocks, WPB * 64, 0, stream>>>(x, co, W, lns, lnb, out, n_tok);
}